// Round 2
// baseline (4278.500 us; speedup 1.0000x reference)
//
#include <hip/hip_runtime.h>

#define CN0 100000
#define CN1 300000
#define CN2 200000
#define EA0 600000
#define EA1 1200000
#define EC2 600000
#define EB1 600000
#define EB2 600000

__device__ __forceinline__ float lrelu(float v) { return v >= 0.f ? v : 0.2f * v; }

// float atomic max via monotone int/uint trick; init bits must be 0xFFFFFFFF or -inf
__device__ __forceinline__ void atomicMaxF(float* a, float v) {
    if (v >= 0.f) atomicMax((int*)a, __float_as_int(v));
    else          atomicMin((unsigned int*)a, __float_as_uint(v));
}

// Y[n,64] = X[n,64] @ W[64,64]; one wave per 32 rows; W column held per-lane in regs
__global__ void mm64(const float* __restrict__ X, const float* __restrict__ W,
                     float* __restrict__ Y, int n) {
    int lane = threadIdx.x & 63;
    int gw = blockIdx.x * (blockDim.x >> 6) + (threadIdx.x >> 6);
    float wc[64];
#pragma unroll
    for (int j = 0; j < 64; ++j) wc[j] = W[j * 64 + lane];
    int i0 = gw * 32;
    for (int r = 0; r < 32; ++r) {
        int i = i0 + r;
        if (i >= n) break;
        float xv = X[(size_t)i * 64 + lane];
        float acc = 0.f;
#pragma unroll
        for (int j = 0; j < 64; ++j) acc = fmaf(__shfl(xv, j, 64), wc[j], acc);
        Y[(size_t)i * 64 + lane] = acc;
    }
}

// uu[j] = sum_k W[j,k]*a[k] ; uu[64+j] = sum_k W[j,k]*a[64+k]   (launch 1 block x 64)
__global__ void uvec_k(const float* __restrict__ W, const float* __restrict__ a2c,
                       float* __restrict__ uu) {
    int j = threadIdx.x;
    float s0 = 0.f, s1 = 0.f;
    for (int k = 0; k < 64; ++k) {
        float w = W[j * 64 + k];
        s0 = fmaf(w, a2c[k], s0);
        s1 = fmaf(w, a2c[64 + k], s1);
    }
    uu[j] = s0;
    uu[64 + j] = s1;
}

// p[i] = X[i,:]@uu[0:64], q[i] = X[i,:]@uu[64:128]; one wave per row
__global__ void proj2(const float* __restrict__ X, const float* __restrict__ uu,
                      float* __restrict__ p, float* __restrict__ q, int n) {
    int lane = threadIdx.x & 63;
    int row = blockIdx.x * (blockDim.x >> 6) + (threadIdx.x >> 6);
    if (row >= n) return;
    float xv = X[(size_t)row * 64 + lane];
    float a = xv * uu[lane];
    float b = xv * uu[64 + lane];
#pragma unroll
    for (int off = 32; off; off >>= 1) {
        a += __shfl_xor(a, off, 64);
        b += __shfl_xor(b, off, 64);
    }
    if (lane == 0) { p[row] = a; q[row] = b; }
}

// logit[e] = lrelu(pa[ia[e]] + pb[ib[e]]); segmax[seg[e]] = max(...)
__global__ void k_logits(const float* __restrict__ pa, const int* __restrict__ ia,
                         const float* __restrict__ pb, const int* __restrict__ ib,
                         const int* __restrict__ seg, float* __restrict__ logit,
                         float* __restrict__ segmax, int E) {
    int e = blockIdx.x * blockDim.x + threadIdx.x;
    if (e >= E) return;
    float l = lrelu(pa[ia[e]] + pb[ib[e]]);
    logit[e] = l;
    atomicMaxF(&segmax[seg[e]], l);
}

// w[e] = exp(logit[e]-segmax[seg]); segsum[seg] += w
__global__ void k_expsum(const int* __restrict__ seg, const float* __restrict__ segmax,
                         float* __restrict__ w, float* __restrict__ segsum, int E) {
    int e = blockIdx.x * blockDim.x + threadIdx.x;
    if (e >= E) return;
    int s = seg[e];
    float v = expf(w[e] - segmax[s]);
    w[e] = v;
    unsafeAtomicAdd(&segsum[s], v);
}

// out[seg[e],k] += (w[e]/segsum[seg[e]]) * M[vidx[e],k]   (64 threads per edge)
__global__ void k_agg(const int* __restrict__ seg, const int* __restrict__ vidx,
                      const float* __restrict__ w, const float* __restrict__ segsum,
                      const float* __restrict__ M, float* __restrict__ out, int E) {
    int t = blockIdx.x * blockDim.x + threadIdx.x;
    int e = t >> 6;
    int k = t & 63;
    if (e >= E) return;
    int s = seg[e];
    float att = w[e] / segsum[s];
    float val = att * M[(size_t)vidx[e] * 64 + k];
    unsafeAtomicAdd(&out[(size_t)s * 64 + k], val);
}

extern "C" void kernel_launch(void* const* d_in, const int* in_sizes, int n_in,
                              void* d_out, int out_size, void* d_ws, size_t ws_size,
                              hipStream_t stream) {
    (void)in_sizes; (void)n_in; (void)ws_size;
    const float* x0 = (const float*)d_in[0];
    const float* x1 = (const float*)d_in[1];
    const float* x2 = (const float*)d_in[2];
    const int* adj0r = (const int*)d_in[3];
    const int* adj0c = (const int*)d_in[4];
    const int* adj1r = (const int*)d_in[5];
    const int* adj1c = (const int*)d_in[6];
    const int* co2r = (const int*)d_in[7];
    const int* co2c = (const int*)d_in[8];
    const int* i1r = (const int*)d_in[9];   // N0 range (target rows)
    const int* i1c = (const int*)d_in[10];  // N1 range (source cols)
    const int* i2r = (const int*)d_in[11];  // N1 range
    const int* i2c = (const int*)d_in[12];  // N2 range
    const float* W_h0_l1 = (const float*)d_in[13];
    const float* W_h0_l2 = (const float*)d_in[14];
    const float* W_h1_l2 = (const float*)d_in[15];
    const float* W_h2_l2 = (const float*)d_in[16];
    const float* Ws01_l1 = (const float*)d_in[17];
    const float* Wt01_l1 = (const float*)d_in[18];
    const float* Ws12_l1 = (const float*)d_in[19];
    const float* Wt12_l1 = (const float*)d_in[20];
    const float* Ws01_l2 = (const float*)d_in[21];
    const float* Wt01_l2 = (const float*)d_in[22];
    const float* Ws12_l2 = (const float*)d_in[23];
    const float* Wt12_l2 = (const float*)d_in[24];
    const float* a_h0_l1 = (const float*)d_in[25];
    const float* a_h0_l2 = (const float*)d_in[26];
    const float* a_h1_l2 = (const float*)d_in[27];
    const float* a_h2_l2 = (const float*)d_in[28];
    const float* a01_l1 = (const float*)d_in[29];
    const float* a12_l1 = (const float*)d_in[30];
    const float* a01_l2 = (const float*)d_in[31];
    const float* a12_l2 = (const float*)d_in[32];

    float* ws = (float*)d_ws;
    // workspace layout (floats); peak ~48.4M floats ~ 194 MB
    float* A    = ws;                       // N1*64 = 19.2M
    float* B    = A + 19200000;             // N1*64
    float* Cb   = B + 19200000;             // N0*64 = 6.4M
    float* elog = Cb + 6400000;             // 1.2M
    float* sgm  = elog + 1200000;           // 300k
    float* sgs  = sgm + 300000;             // 300k
    float* s0   = sgs + 300000;             // 6 x 300k scalar buffers
    float* s1   = s0 + 300000;
    float* s2   = s1 + 300000;
    float* s3   = s2 + 300000;
    float* s4   = s3 + 300000;
    float* s5   = s4 + 300000;
    float* uu   = s5 + 300000;              // 128

    float* r0 = (float*)d_out;              // x_0 region [N0,64]
    float* r1 = r0 + (size_t)CN0 * 64;      // x_1 region [N1,64]
    float* r2 = r1 + (size_t)CN1 * 64;      // x_2 region [N2,64]

    auto MM = [&](const float* X, const float* W, float* Y, int n) {
        mm64<<<dim3((n + 127) / 128), dim3(256), 0, stream>>>(X, W, Y, n);
    };
    auto PROJ = [&](const float* X, const float* W, const float* a2, float* p, float* q, int n) {
        uvec_k<<<dim3(1), dim3(64), 0, stream>>>(W, a2, uu);
        proj2<<<dim3((n + 3) / 4), dim3(256), 0, stream>>>(X, uu, p, q, n);
    };
    auto SMAX_AGG = [&](const float* pa, const int* ia, const float* pb, const int* ib,
                        const int* seg, int nseg, const int* vidx, const float* M,
                        float* out, int E) {
        hipMemsetAsync(sgm, 0xFF, (size_t)nseg * 4, stream);  // 0xFFFFFFFF = -NaN bits, identity for both atomic paths
        hipMemsetAsync(sgs, 0, (size_t)nseg * 4, stream);
        int gb = (E + 255) / 256;
        k_logits<<<dim3(gb), dim3(256), 0, stream>>>(pa, ia, pb, ib, seg, elog, sgm, E);
        k_expsum<<<dim3(gb), dim3(256), 0, stream>>>(seg, sgm, elog, sgs, E);
        int gb2 = (int)(((size_t)E * 64 + 255) / 256);
        k_agg<<<dim3(gb2), dim3(256), 0, stream>>>(seg, vidx, elog, sgs, M, out, E);
    };

    // ======== LEVEL 1 (accumulate x*_l1 into d_out regions) ========
    hipMemsetAsync(d_out, 0, (size_t)out_size * 4, stream);

    // hbs0_l1: m0 = x0@W ; msgs -> r0
    MM(x0, W_h0_l1, Cb, CN0);
    PROJ(x0, W_h0_l1, a_h0_l1, s0, s1, CN0);
    SMAX_AGG(s0, adj0r, s1, adj0c, adj0r, CN0, adj0c, Cb, r0, EA0);

    // hbns01_l1: sm = x1@Ws (A), tm = x0@Wt (Cb)
    MM(x1, Ws01_l1, A, CN1);
    MM(x0, Wt01_l1, Cb, CN0);
    PROJ(x1, Ws01_l1, a01_l1, s0, s1, CN1);  // ps, qs
    PROJ(x0, Wt01_l1, a01_l1, s2, s3, CN0);  // pt, qt
    // e: lrelu(ps[s_col]+qt[t_row]); seg=t_rows(N0); msg_t = att*sm[s_col] -> r0
    SMAX_AGG(s0, i1c, s3, i1r, i1r, CN0, i1c, A, r0, EB1);
    // f: lrelu(pt[t_row]+qs[s_col]); seg=s_cols(N1); msg_s = att*tm[t_row] -> r1
    SMAX_AGG(s2, i1r, s1, i1c, i1c, CN1, i1r, Cb, r1, EB1);

    // hbns12_l1: sm = x2@Ws (A), tm = x1@Wt (B)
    MM(x2, Ws12_l1, A, CN2);
    MM(x1, Wt12_l1, B, CN1);
    PROJ(x2, Ws12_l1, a12_l1, s0, s1, CN2);  // ps, qs
    PROJ(x1, Wt12_l1, a12_l1, s2, s3, CN1);  // pt, qt
    SMAX_AGG(s0, i2c, s3, i2r, i2r, CN1, i2c, A, r1, EB2);  // x_2_to_1 -> r1
    SMAX_AGG(s2, i2r, s1, i2c, i2c, CN2, i2r, B, r2, EB2);  // x_1_to_2 -> r2

    // ======== LEVEL 2 ========
    // ---- rank 0 phase: consume r0 (=x0_l1), then overwrite with x_0_out
    MM(r0, W_h0_l2, A, CN0);                 // m00
    MM(r0, Wt01_l2, Cb, CN0);                // tm01 (kept for rank-1 phase)
    PROJ(r0, W_h0_l2, a_h0_l2, s0, s1, CN0); // hbs0 p,q
    PROJ(r0, Wt01_l2, a01_l2, s4, s5, CN0);  // pt01 -> s4 (a0-part); s5 junk
    hipMemsetAsync(r0, 0, (size_t)CN0 * 64 * 4, stream);
    SMAX_AGG(s0, adj0r, s1, adj0c, adj0r, CN0, adj0c, A, r0, EA0);  // x_0_out

    // ---- rank 1 phase: consume r1 (=x1_l1), then overwrite with x_1_out
    MM(r1, W_h1_l2, A, CN1);                 // m11
    MM(r1, Wt12_l2, B, CN1);                 // tm12 (kept for rank-2 phase)
    PROJ(r1, W_h1_l2, a_h1_l2, s0, s1, CN1); // hbs1 p,q
    PROJ(r1, Ws01_l2, a01_l2, s5, s2, CN1);  // qs01 -> s2 (a1-part); s5 junk
    PROJ(r1, Wt12_l2, a12_l2, s3, s5, CN1);  // pt12 -> s3 (a0-part); s5 junk
    hipMemsetAsync(r1, 0, (size_t)CN1 * 64 * 4, stream);
    SMAX_AGG(s0, adj1r, s1, adj1c, adj1r, CN1, adj1c, A, r1, EA1);  // x_1_to_1
    // hbns01_l2 f-direction only: seg=i1c(N1), values tm01[i1r]
    SMAX_AGG(s4, i1r, s2, i1c, i1c, CN1, i1r, Cb, r1, EB1);         // + x_0_to_1

    // ---- rank 2 phase: consume r2 (=x2_l1), then overwrite with x_2_out
    MM(r2, W_h2_l2, A, CN2);                 // m22
    PROJ(r2, W_h2_l2, a_h2_l2, s0, s1, CN2); // hbs2 p,q
    PROJ(r2, Ws12_l2, a12_l2, s5, s2, CN2);  // qs12 -> s2 (a1-part); s5 junk
    hipMemsetAsync(r2, 0, (size_t)CN2 * 64 * 4, stream);
    SMAX_AGG(s0, co2r, s1, co2c, co2r, CN2, co2c, A, r2, EC2);      // x_2_to_2
    // hbns12_l2 f-direction only: seg=i2c(N2), values tm12[i2r]
    SMAX_AGG(s3, i2r, s2, i2c, i2c, CN2, i2r, B, r2, EB2);          // + x_1_to_2
}

// Round 3
// 3657.071 us; speedup vs baseline: 1.1699x; 1.1699x over previous
//
#include <hip/hip_runtime.h>

#define CN0 100000
#define CN1 300000
#define CN2 200000
#define EA0 600000
#define EA1 1200000
#define EC2 600000
#define EB1 600000
#define EB2 600000

__device__ __forceinline__ float lrelu(float v) { return v >= 0.f ? v : 0.2f * v; }

// ---------------- CSR build kernels ----------------

__global__ void k_hist(const int* __restrict__ seg, int* __restrict__ rp, int E) {
    int e = blockIdx.x * blockDim.x + threadIdx.x;
    if (e < E) atomicAdd(&rp[seg[e] + 1], 1);
}

// per-block inclusive scan of d[0..n), block sums to bsum
__global__ void k_blkscan(int* __restrict__ d, int n, int* __restrict__ bsum) {
    __shared__ int sh[256];
    int i = blockIdx.x * 256 + threadIdx.x;
    sh[threadIdx.x] = (i < n) ? d[i] : 0;
    __syncthreads();
    for (int off = 1; off < 256; off <<= 1) {
        int t = (threadIdx.x >= (unsigned)off) ? sh[threadIdx.x - off] : 0;
        __syncthreads();
        sh[threadIdx.x] += t;
        __syncthreads();
    }
    if (i < n) d[i] = sh[threadIdx.x];
    if (threadIdx.x == 255) bsum[blockIdx.x] = sh[255];
}

// single-block inclusive scan of bsum[0..nb)
__global__ void k_scanb(int* __restrict__ bsum, int nb) {
    __shared__ int sh[256];
    __shared__ int carry;
    if (threadIdx.x == 0) carry = 0;
    __syncthreads();
    for (int base = 0; base < nb; base += 256) {
        int i = base + threadIdx.x;
        sh[threadIdx.x] = (i < nb) ? bsum[i] : 0;
        __syncthreads();
        for (int off = 1; off < 256; off <<= 1) {
            int t = (threadIdx.x >= (unsigned)off) ? sh[threadIdx.x - off] : 0;
            __syncthreads();
            sh[threadIdx.x] += t;
            __syncthreads();
        }
        if (i < nb) bsum[i] = sh[threadIdx.x] + carry;
        __syncthreads();
        if (threadIdx.x == 0) carry += sh[255];
        __syncthreads();
    }
}

__global__ void k_addoff(int* __restrict__ d, const int* __restrict__ bsum, int n) {
    int i = blockIdx.x * 256 + threadIdx.x;
    if (i < n && blockIdx.x > 0) d[i] += bsum[blockIdx.x - 1];
}

__global__ void k_scatter(const int* __restrict__ seg, const int* __restrict__ vidx,
                          const int* __restrict__ rp, int* __restrict__ cnt,
                          int* __restrict__ vP, int E) {
    int e = blockIdx.x * blockDim.x + threadIdx.x;
    if (e >= E) return;
    int s = seg[e];
    int pos = rp[s] + atomicAdd(&cnt[s], 1);
    vP[pos] = vidx[e];
}

// ---------------- compute kernels ----------------

// Y[n,64] = X[n,64] @ W[64,64]; optionally fused p=Y@a[0:64], q=Y@a[64:128]
template <int FUSE>
__global__ void mm64k(const float* __restrict__ X, const float* __restrict__ W,
                      const float* __restrict__ a, float* __restrict__ Y,
                      float* __restrict__ p, float* __restrict__ q, int n) {
    int lane = threadIdx.x & 63;
    int gw = blockIdx.x * (blockDim.x >> 6) + (threadIdx.x >> 6);
    float wc[64];
#pragma unroll
    for (int j = 0; j < 64; ++j) wc[j] = W[j * 64 + lane];
    float a0 = 0.f, a1 = 0.f;
    if (FUSE) { a0 = a[lane]; a1 = a[64 + lane]; }
    int i0 = gw * 32;
    for (int r = 0; r < 32; ++r) {
        int i = i0 + r;
        if (i >= n) break;
        float xv = X[(size_t)i * 64 + lane];
        float acc = 0.f;
#pragma unroll
        for (int j = 0; j < 64; ++j) acc = fmaf(__shfl(xv, j, 64), wc[j], acc);
        Y[(size_t)i * 64 + lane] = acc;
        if (FUSE) {
            float pa = acc * a0, qa = acc * a1;
#pragma unroll
            for (int off = 32; off; off >>= 1) {
                pa += __shfl_xor(pa, off, 64);
                qa += __shfl_xor(qa, off, 64);
            }
            if (lane == 0) { p[i] = pa; q[i] = qa; }
        }
    }
}

// uu[j] = W[j,:]@a[0:64]; uu[64+j] = W[j,:]@a[64:128]   (1 block x 64)
__global__ void uvec_k(const float* __restrict__ W, const float* __restrict__ a2c,
                       float* __restrict__ uu) {
    int j = threadIdx.x;
    float s0 = 0.f, s1 = 0.f;
    for (int k = 0; k < 64; ++k) {
        float w = W[j * 64 + k];
        s0 = fmaf(w, a2c[k], s0);
        s1 = fmaf(w, a2c[64 + k], s1);
    }
    uu[j] = s0;
    uu[64 + j] = s1;
}

// p[i] = X[i,:]@uu[0:64], q[i] = X[i,:]@uu[64:128]; one wave per row
__global__ void proj2(const float* __restrict__ X, const float* __restrict__ uu,
                      float* __restrict__ p, float* __restrict__ q, int n) {
    int lane = threadIdx.x & 63;
    int row = blockIdx.x * (blockDim.x >> 6) + (threadIdx.x >> 6);
    if (row >= n) return;
    float xv = X[(size_t)row * 64 + lane];
    float a = xv * uu[lane];
    float b = xv * uu[64 + lane];
#pragma unroll
    for (int off = 32; off; off >>= 1) {
        a += __shfl_xor(a, off, 64);
        b += __shfl_xor(b, off, 64);
    }
    if (lane == 0) { p[row] = a; q[row] = b; }
}

// One wave per segment: softmax over edges + weighted row gather, single row write.
// logit(j) = lrelu(ps[s] + pv[vP[j]]);  out[s,:] (=|+=) sum_j att_j * M[vP[j],:]
__global__ void k_seg_attn(const int* __restrict__ rp, const int* __restrict__ vP,
                           const float* __restrict__ ps, const float* __restrict__ pv,
                           const float* __restrict__ M, float* __restrict__ out,
                           int nseg, int accum) {
    int lane = threadIdx.x & 63;
    int s = blockIdx.x * (blockDim.x >> 6) + (threadIdx.x >> 6);
    if (s >= nseg) return;
    int beg = rp[s], end = rp[s + 1];
    size_t orow = (size_t)s * 64 + lane;
    int nE = end - beg;
    if (nE <= 0) {
        if (!accum) out[orow] = 0.f;
        return;
    }
    float pss = ps[s];
    float acc = 0.f;
    if (nE <= 64) {  // fast path: one chunk, logits stay in registers
        int j = beg + lane;
        int v = (j < end) ? vP[j] : 0;
        float l = (j < end) ? lrelu(pss + pv[v]) : -3.4e38f;
        float mx = l;
#pragma unroll
        for (int off = 32; off; off >>= 1) mx = fmaxf(mx, __shfl_xor(mx, off, 64));
        float ev = (j < end) ? __expf(l - mx) : 0.f;
        float ssum = ev;
#pragma unroll
        for (int off = 32; off; off >>= 1) ssum += __shfl_xor(ssum, off, 64);
        float att = ev / ssum;
        for (int t = 0; t < nE; ++t) {
            float w = __shfl(att, t, 64);
            int vv = __shfl(v, t, 64);
            acc = fmaf(w, M[(size_t)vv * 64 + lane], acc);
        }
    } else {  // general path (rare long segments)
        float mx = -3.4e38f;
        for (int j0 = beg; j0 < end; j0 += 64) {
            int j = j0 + lane;
            float l = (j < end) ? lrelu(pss + pv[vP[j]]) : -3.4e38f;
            mx = fmaxf(mx, l);
        }
#pragma unroll
        for (int off = 32; off; off >>= 1) mx = fmaxf(mx, __shfl_xor(mx, off, 64));
        float ssum = 0.f;
        for (int j0 = beg; j0 < end; j0 += 64) {
            int j = j0 + lane;
            ssum += (j < end) ? __expf(lrelu(pss + pv[vP[j]]) - mx) : 0.f;
        }
#pragma unroll
        for (int off = 32; off; off >>= 1) ssum += __shfl_xor(ssum, off, 64);
        float inv = 1.f / ssum;
        for (int j0 = beg; j0 < end; j0 += 64) {
            int j = j0 + lane;
            int v = (j < end) ? vP[j] : 0;
            float ev = (j < end) ? __expf(lrelu(pss + pv[v]) - mx) * inv : 0.f;
            int cnt = min(64, end - j0);
            for (int t = 0; t < cnt; ++t) {
                float w = __shfl(ev, t, 64);
                int vv = __shfl(v, t, 64);
                acc = fmaf(w, M[(size_t)vv * 64 + lane], acc);
            }
        }
    }
    if (accum) out[orow] += acc;
    else out[orow] = acc;
}

extern "C" void kernel_launch(void* const* d_in, const int* in_sizes, int n_in,
                              void* d_out, int out_size, void* d_ws, size_t ws_size,
                              hipStream_t stream) {
    (void)in_sizes; (void)n_in; (void)ws_size; (void)out_size;
    const float* x0 = (const float*)d_in[0];
    const float* x1 = (const float*)d_in[1];
    const float* x2 = (const float*)d_in[2];
    const int* adj0r = (const int*)d_in[3];
    const int* adj0c = (const int*)d_in[4];
    const int* adj1r = (const int*)d_in[5];
    const int* adj1c = (const int*)d_in[6];
    const int* co2r = (const int*)d_in[7];
    const int* co2c = (const int*)d_in[8];
    const int* i1r = (const int*)d_in[9];   // N0 range (target rows)
    const int* i1c = (const int*)d_in[10];  // N1 range (source cols)
    const int* i2r = (const int*)d_in[11];  // N1 range
    const int* i2c = (const int*)d_in[12];  // N2 range
    const float* W_h0_l1 = (const float*)d_in[13];
    const float* W_h0_l2 = (const float*)d_in[14];
    const float* W_h1_l2 = (const float*)d_in[15];
    const float* W_h2_l2 = (const float*)d_in[16];
    const float* Ws01_l1 = (const float*)d_in[17];
    const float* Wt01_l1 = (const float*)d_in[18];
    const float* Ws12_l1 = (const float*)d_in[19];
    const float* Wt12_l1 = (const float*)d_in[20];
    const float* Ws01_l2 = (const float*)d_in[21];
    const float* Wt01_l2 = (const float*)d_in[22];
    const float* Ws12_l2 = (const float*)d_in[23];
    const float* Wt12_l2 = (const float*)d_in[24];
    const float* a_h0_l1 = (const float*)d_in[25];
    const float* a_h0_l2 = (const float*)d_in[26];
    const float* a_h1_l2 = (const float*)d_in[27];
    const float* a_h2_l2 = (const float*)d_in[28];
    const float* a01_l1 = (const float*)d_in[29];
    const float* a12_l1 = (const float*)d_in[30];
    const float* a01_l2 = (const float*)d_in[31];
    const float* a12_l2 = (const float*)d_in[32];

    // -------- workspace layout (4B units), total ~53.2M (~213 MB) --------
    float* ws = (float*)d_ws;
    float* A   = ws;                         // [N1,64]
    float* B   = A + 19200000;               // [N1,64]
    float* Cb  = B + 19200000;               // [N0,64]
    float* s0  = Cb + 6400000;
    float* s1  = s0 + 300000;
    float* s2  = s1 + 300000;
    float* s3  = s2 + 300000;
    float* s4  = s3 + 300000;
    float* s5  = s4 + 300000;
    float* uu  = s5 + 300000;                // 128
    int* ip = (int*)(uu + 128);
    int* rpA0 = ip;            ip += CN0 + 1;  // P_adj0
    int* rpE1 = ip;            ip += CN0 + 1;  // P_e01 (seg=i1r)
    int* rpF1 = ip;            ip += CN1 + 1;  // P_f01 (seg=i1c)
    int* rpE2 = ip;            ip += CN1 + 1;  // P_e12 (seg=i2r)
    int* rpF2 = ip;            ip += CN2 + 1;  // P_f12 (seg=i2c)
    int* rpA1 = ip;            ip += CN1 + 1;  // P_adj1
    int* rpC2 = ip;            ip += CN2 + 1;  // P_co2
    int* vA0 = ip;             ip += EA0;
    int* vE1 = ip;             ip += EB1;
    int* vF1 = ip;             ip += EB1;
    int* vE2 = ip;             ip += EB2;
    int* vF2 = ip;             ip += EB2;
    int* vA1 = ip;             ip += EA1;
    int* vC2 = ip;             ip += EC2;
    int* cnt = ip;             ip += 300000;
    int* bsum = ip;            ip += 2048;

    float* r0 = (float*)d_out;               // x_0 region [N0,64]
    float* r1 = r0 + (size_t)CN0 * 64;       // x_1 region [N1,64]
    float* r2 = r1 + (size_t)CN1 * 64;       // x_2 region [N2,64]

    auto CSR = [&](const int* seg, const int* vidx, int* rp, int* vP, int nseg, int E) {
        hipMemsetAsync(rp, 0, (size_t)(nseg + 1) * 4, stream);
        k_hist<<<dim3((E + 255) / 256), dim3(256), 0, stream>>>(seg, rp, E);
        int nb = (nseg + 255) / 256;
        k_blkscan<<<dim3(nb), dim3(256), 0, stream>>>(rp + 1, nseg, bsum);
        k_scanb<<<dim3(1), dim3(256), 0, stream>>>(bsum, nb);
        k_addoff<<<dim3(nb), dim3(256), 0, stream>>>(rp + 1, bsum, nseg);
        hipMemsetAsync(cnt, 0, (size_t)nseg * 4, stream);
        k_scatter<<<dim3((E + 255) / 256), dim3(256), 0, stream>>>(seg, vidx, rp, cnt, vP, E);
    };
    auto MMF = [&](const float* X, const float* W, const float* a, float* Y,
                   float* p, float* q, int n) {
        mm64k<1><<<dim3((n + 127) / 128), dim3(256), 0, stream>>>(X, W, a, Y, p, q, n);
    };
    auto PROJ = [&](const float* X, const float* W, const float* a2, float* p, float* q, int n) {
        uvec_k<<<dim3(1), dim3(64), 0, stream>>>(W, a2, uu);
        proj2<<<dim3((n + 3) / 4), dim3(256), 0, stream>>>(X, uu, p, q, n);
    };
    auto AGG = [&](const int* rp, const int* vP, const float* ps, const float* pv,
                   const float* M, float* out, int nseg, int accum) {
        k_seg_attn<<<dim3((nseg + 3) / 4), dim3(256), 0, stream>>>(rp, vP, ps, pv, M, out,
                                                                   nseg, accum);
    };

    // ======== CSR builds (index patterns, reused by all aggregations) ========
    CSR(adj0r, adj0c, rpA0, vA0, CN0, EA0);
    CSR(i1r, i1c, rpE1, vE1, CN0, EB1);
    CSR(i1c, i1r, rpF1, vF1, CN1, EB1);
    CSR(i2r, i2c, rpE2, vE2, CN1, EB2);
    CSR(i2c, i2r, rpF2, vF2, CN2, EB2);
    CSR(adj1r, adj1c, rpA1, vA1, CN1, EA1);
    CSR(co2r, co2c, rpC2, vC2, CN2, EC2);

    // ======== LEVEL 1 (x*_l1 built in d_out regions) ========
    // hbs0_l1: m0 = x0@W -> Cb ; p,q -> s0,s1
    MMF(x0, W_h0_l1, a_h0_l1, Cb, s0, s1, CN0);
    AGG(rpA0, vA0, s0, s1, Cb, r0, CN0, 0);                 // x_0_to_0 (write)

    // hbns01_l1: sm = x1@Ws -> A (ps,qs -> s0,s1); tm = x0@Wt -> Cb (pt,qt -> s2,s3)
    MMF(x1, Ws01_l1, a01_l1, A, s0, s1, CN1);
    MMF(x0, Wt01_l1, a01_l1, Cb, s2, s3, CN0);
    AGG(rpE1, vE1, s3, s0, A, r0, CN0, 1);                  // + x_1_to_0 (seg-side qt=s3, v-side ps=s0)
    AGG(rpF1, vF1, s1, s2, Cb, r1, CN1, 0);                 // x_0_to_1 (seg qs=s1, v pt=s2)

    // hbns12_l1: sm = x2@Ws -> A (s0,s1); tm = x1@Wt -> B (s2,s3)
    MMF(x2, Ws12_l1, a12_l1, A, s0, s1, CN2);
    MMF(x1, Wt12_l1, a12_l1, B, s2, s3, CN1);
    AGG(rpE2, vE2, s3, s0, A, r1, CN1, 1);                  // + x_2_to_1
    AGG(rpF2, vF2, s1, s2, B, r2, CN2, 0);                  // x_1_to_2 (write)

    // ======== LEVEL 2 ========
    // ---- rank 0: consume r0 (=x0_l1), then overwrite with x_0_out
    MMF(r0, W_h0_l2, a_h0_l2, A, s0, s1, CN0);              // m00
    MMF(r0, Wt01_l2, a01_l2, Cb, s4, s5, CN0);              // tm01; pt01 -> s4
    AGG(rpA0, vA0, s0, s1, A, r0, CN0, 0);                  // x_0_out (write, r0 consumed)

    // ---- rank 1: consume r1 (=x1_l1), then overwrite with x_1_out
    MMF(r1, W_h1_l2, a_h1_l2, A, s0, s1, CN1);              // m11
    MMF(r1, Wt12_l2, a12_l2, B, s3, s5, CN1);               // tm12; pt12 -> s3
    PROJ(r1, Ws01_l2, a01_l2, s5, s2, CN1);                 // qs01 -> s2 (sm matmul not needed)
    AGG(rpA1, vA1, s0, s1, A, r1, CN1, 0);                  // x_1_to_1 (write)
    AGG(rpF1, vF1, s2, s4, Cb, r1, CN1, 1);                 // + x_0_to_1 (seg qs01=s2, v pt01=s4)

    // ---- rank 2: consume r2 (=x2_l1), then overwrite with x_2_out
    MMF(r2, W_h2_l2, a_h2_l2, A, s0, s1, CN2);              // m22
    PROJ(r2, Ws12_l2, a12_l2, s5, s2, CN2);                 // qs12 -> s2
    AGG(rpC2, vC2, s0, s1, A, r2, CN2, 0);                  // x_2_to_2 (write)
    AGG(rpF2, vF2, s2, s3, B, r2, CN2, 1);                  // + x_1_to_2 (seg qs12=s2, v pt12=s3)
}

// Round 4
// 1931.735 us; speedup vs baseline: 2.2148x; 1.8932x over previous
//
#include <hip/hip_runtime.h>

#define CN0 100000
#define CN1 300000
#define CN2 200000
#define EA0 600000
#define EA1 1200000
#define EC2 600000
#define EB1 600000
#define EB2 600000

typedef __attribute__((ext_vector_type(8))) short short8;
typedef __attribute__((ext_vector_type(4))) float f32x4;

__device__ __forceinline__ float lrelu(float v) { return v >= 0.f ? v : 0.2f * v; }
__device__ __forceinline__ unsigned short btop(float x) {
    return (unsigned short)(__float_as_uint(x) >> 16);
}

// ---------------- CSR build kernels ----------------

__global__ void k_hist(const int* __restrict__ seg, int* __restrict__ rp, int E) {
    int e = blockIdx.x * blockDim.x + threadIdx.x;
    if (e < E) atomicAdd(&rp[seg[e] + 1], 1);
}

__global__ void k_blkscan(int* __restrict__ d, int n, int* __restrict__ bsum) {
    __shared__ int sh[256];
    int i = blockIdx.x * 256 + threadIdx.x;
    sh[threadIdx.x] = (i < n) ? d[i] : 0;
    __syncthreads();
    for (int off = 1; off < 256; off <<= 1) {
        int t = (threadIdx.x >= (unsigned)off) ? sh[threadIdx.x - off] : 0;
        __syncthreads();
        sh[threadIdx.x] += t;
        __syncthreads();
    }
    if (i < n) d[i] = sh[threadIdx.x];
    if (threadIdx.x == 255) bsum[blockIdx.x] = sh[255];
}

__global__ void k_scanb(int* __restrict__ bsum, int nb) {
    __shared__ int sh[256];
    __shared__ int carry;
    if (threadIdx.x == 0) carry = 0;
    __syncthreads();
    for (int base = 0; base < nb; base += 256) {
        int i = base + threadIdx.x;
        sh[threadIdx.x] = (i < nb) ? bsum[i] : 0;
        __syncthreads();
        for (int off = 1; off < 256; off <<= 1) {
            int t = (threadIdx.x >= (unsigned)off) ? sh[threadIdx.x - off] : 0;
            __syncthreads();
            sh[threadIdx.x] += t;
            __syncthreads();
        }
        if (i < nb) bsum[i] = sh[threadIdx.x] + carry;
        __syncthreads();
        if (threadIdx.x == 0) carry += sh[255];
        __syncthreads();
    }
}

__global__ void k_addoff(int* __restrict__ d, const int* __restrict__ bsum, int n) {
    int i = blockIdx.x * 256 + threadIdx.x;
    if (i < n && blockIdx.x > 0) d[i] += bsum[blockIdx.x - 1];
}

__global__ void k_scatter(const int* __restrict__ seg, const int* __restrict__ vidx,
                          const int* __restrict__ rp, int* __restrict__ cnt,
                          int* __restrict__ vP, int E) {
    int e = blockIdx.x * blockDim.x + threadIdx.x;
    if (e >= E) return;
    int s = seg[e];
    int pos = rp[s] + atomicAdd(&cnt[s], 1);
    vP[pos] = vidx[e];
}

// ---------------- MFMA matmul (bf16x3 split) ----------------
// Y = X @ W ; fused p = Y@a[0:64], q = Y@a[64:128]
// Wave tile: 16 rows x 64 cols (4 N-tiles of mfma_f32_16x16x32_bf16, K=64 in 2 halves)
__global__ void mm64_mfma(const float* __restrict__ X, const float* __restrict__ W,
                          const float* __restrict__ a, float* __restrict__ Y,
                          float* __restrict__ p, float* __restrict__ q, int nchunk) {
    int lane = threadIdx.x & 63;
    int l15 = lane & 15, lq = lane >> 4;
    int wid = blockIdx.x * (blockDim.x >> 6) + (threadIdx.x >> 6);
    int nw = gridDim.x * (blockDim.x >> 6);

    // B fragments (hoisted): element j of tile t, K-half h = W[h*32+lq*8+j][16t+l15]
    short8 bh[4][2], bl[4][2];
#pragma unroll
    for (int t = 0; t < 4; ++t)
#pragma unroll
        for (int h = 0; h < 2; ++h) {
            const float* wp = W + (size_t)(h * 32 + lq * 8) * 64 + 16 * t + l15;
#pragma unroll
            for (int j = 0; j < 8; ++j) {
                float wv = wp[(size_t)j * 64];
                unsigned short hi = btop(wv);
                float rem = wv - __uint_as_float((unsigned)hi << 16);
                bh[t][h][j] = (short)hi;
                bl[t][h][j] = (short)btop(rem);
            }
        }
    float av0[4], av1[4];
#pragma unroll
    for (int t = 0; t < 4; ++t) {
        av0[t] = a[16 * t + l15];
        av1[t] = a[64 + 16 * t + l15];
    }

    for (int c = wid; c < nchunk; c += nw) {
        int base = c * 16;
        f32x4 acc[4];
#pragma unroll
        for (int t = 0; t < 4; ++t) acc[t] = (f32x4){0.f, 0.f, 0.f, 0.f};
#pragma unroll
        for (int h = 0; h < 2; ++h) {
            const f32x4* xp = (const f32x4*)(X + (size_t)(base + l15) * 64 + h * 32 + lq * 8);
            f32x4 x0 = xp[0], x1 = xp[1];
            short8 ah, al;
#pragma unroll
            for (int j = 0; j < 4; ++j) {
                unsigned short h0 = btop(x0[j]);
                float r0 = x0[j] - __uint_as_float((unsigned)h0 << 16);
                ah[j] = (short)h0;
                al[j] = (short)btop(r0);
                unsigned short h1 = btop(x1[j]);
                float r1 = x1[j] - __uint_as_float((unsigned)h1 << 16);
                ah[4 + j] = (short)h1;
                al[4 + j] = (short)btop(r1);
            }
#pragma unroll
            for (int t = 0; t < 4; ++t) {
                acc[t] = __builtin_amdgcn_mfma_f32_16x16x32_bf16(ah, bh[t][h], acc[t], 0, 0, 0);
                acc[t] = __builtin_amdgcn_mfma_f32_16x16x32_bf16(ah, bl[t][h], acc[t], 0, 0, 0);
                acc[t] = __builtin_amdgcn_mfma_f32_16x16x32_bf16(al, bh[t][h], acc[t], 0, 0, 0);
            }
        }
        // store Y: C layout col = l15 + 16t, row = lq*4 + r  [m89-verified]
#pragma unroll
        for (int t = 0; t < 4; ++t)
#pragma unroll
            for (int r = 0; r < 4; ++r)
                Y[(size_t)(base + lq * 4 + r) * 64 + 16 * t + l15] = acc[t][r];
        // fused p,q: per row, dot with a across 16 lanes x 4 tiles
#pragma unroll
        for (int r = 0; r < 4; ++r) {
            float pr = acc[0][r] * av0[0] + acc[1][r] * av0[1] + acc[2][r] * av0[2] + acc[3][r] * av0[3];
            float qr = acc[0][r] * av1[0] + acc[1][r] * av1[1] + acc[2][r] * av1[2] + acc[3][r] * av1[3];
#pragma unroll
            for (int off = 8; off; off >>= 1) {
                pr += __shfl_xor(pr, off, 64);
                qr += __shfl_xor(qr, off, 64);
            }
            if (l15 == 0) {
                p[base + lq * 4 + r] = pr;
                q[base + lq * 4 + r] = qr;
            }
        }
    }
}

// uu[j] = W[j,:]@a[0:64]; uu[64+j] = W[j,:]@a[64:128]   (1 block x 64)
__global__ void uvec_k(const float* __restrict__ W, const float* __restrict__ a2c,
                       float* __restrict__ uu) {
    int j = threadIdx.x;
    float s0 = 0.f, s1 = 0.f;
    for (int k = 0; k < 64; ++k) {
        float w = W[j * 64 + k];
        s0 = fmaf(w, a2c[k], s0);
        s1 = fmaf(w, a2c[64 + k], s1);
    }
    uu[j] = s0;
    uu[64 + j] = s1;
}

// p[i] = X[i,:]@uu[0:64], q[i] = X[i,:]@uu[64:128]; one wave per row
__global__ void proj2(const float* __restrict__ X, const float* __restrict__ uu,
                      float* __restrict__ p, float* __restrict__ q, int n) {
    int lane = threadIdx.x & 63;
    int row = blockIdx.x * (blockDim.x >> 6) + (threadIdx.x >> 6);
    if (row >= n) return;
    float xv = X[(size_t)row * 64 + lane];
    float a = xv * uu[lane];
    float b = xv * uu[64 + lane];
#pragma unroll
    for (int off = 32; off; off >>= 1) {
        a += __shfl_xor(a, off, 64);
        b += __shfl_xor(b, off, 64);
    }
    if (lane == 0) { p[row] = a; q[row] = b; }
}

// One wave per segment: softmax over edges + weighted row gather, single row write.
__global__ void k_seg_attn(const int* __restrict__ rp, const int* __restrict__ vP,
                           const float* __restrict__ ps, const float* __restrict__ pv,
                           const float* __restrict__ M, float* __restrict__ out,
                           int nseg, int accum) {
    int lane = threadIdx.x & 63;
    int s = blockIdx.x * (blockDim.x >> 6) + (threadIdx.x >> 6);
    if (s >= nseg) return;
    int beg = rp[s], end = rp[s + 1];
    size_t orow = (size_t)s * 64 + lane;
    int nE = end - beg;
    if (nE <= 0) {
        if (!accum) out[orow] = 0.f;
        return;
    }
    float pss = ps[s];
    float acc = 0.f;
    if (nE <= 64) {
        int j = beg + lane;
        int v = (j < end) ? vP[j] : 0;
        float l = (j < end) ? lrelu(pss + pv[v]) : -3.4e38f;
        float mx = l;
#pragma unroll
        for (int off = 32; off; off >>= 1) mx = fmaxf(mx, __shfl_xor(mx, off, 64));
        float ev = (j < end) ? __expf(l - mx) : 0.f;
        float ssum = ev;
#pragma unroll
        for (int off = 32; off; off >>= 1) ssum += __shfl_xor(ssum, off, 64);
        float att = ev / ssum;
        for (int t = 0; t < nE; ++t) {
            float w = __shfl(att, t, 64);
            int vv = __shfl(v, t, 64);
            acc = fmaf(w, M[(size_t)vv * 64 + lane], acc);
        }
    } else {
        float mx = -3.4e38f;
        for (int j0 = beg; j0 < end; j0 += 64) {
            int j = j0 + lane;
            float l = (j < end) ? lrelu(pss + pv[vP[j]]) : -3.4e38f;
            mx = fmaxf(mx, l);
        }
#pragma unroll
        for (int off = 32; off; off >>= 1) mx = fmaxf(mx, __shfl_xor(mx, off, 64));
        float ssum = 0.f;
        for (int j0 = beg; j0 < end; j0 += 64) {
            int j = j0 + lane;
            ssum += (j < end) ? __expf(lrelu(pss + pv[vP[j]]) - mx) : 0.f;
        }
#pragma unroll
        for (int off = 32; off; off >>= 1) ssum += __shfl_xor(ssum, off, 64);
        float inv = 1.f / ssum;
        for (int j0 = beg; j0 < end; j0 += 64) {
            int j = j0 + lane;
            int v = (j < end) ? vP[j] : 0;
            float ev = (j < end) ? __expf(lrelu(pss + pv[v]) - mx) * inv : 0.f;
            int cnt = min(64, end - j0);
            for (int t = 0; t < cnt; ++t) {
                float w = __shfl(ev, t, 64);
                int vv = __shfl(v, t, 64);
                acc = fmaf(w, M[(size_t)vv * 64 + lane], acc);
            }
        }
    }
    if (accum) out[orow] += acc;
    else out[orow] = acc;
}

extern "C" void kernel_launch(void* const* d_in, const int* in_sizes, int n_in,
                              void* d_out, int out_size, void* d_ws, size_t ws_size,
                              hipStream_t stream) {
    (void)in_sizes; (void)n_in; (void)ws_size; (void)out_size;
    const float* x0 = (const float*)d_in[0];
    const float* x1 = (const float*)d_in[1];
    const float* x2 = (const float*)d_in[2];
    const int* adj0r = (const int*)d_in[3];
    const int* adj0c = (const int*)d_in[4];
    const int* adj1r = (const int*)d_in[5];
    const int* adj1c = (const int*)d_in[6];
    const int* co2r = (const int*)d_in[7];
    const int* co2c = (const int*)d_in[8];
    const int* i1r = (const int*)d_in[9];
    const int* i1c = (const int*)d_in[10];
    const int* i2r = (const int*)d_in[11];
    const int* i2c = (const int*)d_in[12];
    const float* W_h0_l1 = (const float*)d_in[13];
    const float* W_h0_l2 = (const float*)d_in[14];
    const float* W_h1_l2 = (const float*)d_in[15];
    const float* W_h2_l2 = (const float*)d_in[16];
    const float* Ws01_l1 = (const float*)d_in[17];
    const float* Wt01_l1 = (const float*)d_in[18];
    const float* Ws12_l1 = (const float*)d_in[19];
    const float* Wt12_l1 = (const float*)d_in[20];
    const float* Ws01_l2 = (const float*)d_in[21];
    const float* Wt01_l2 = (const float*)d_in[22];
    const float* Ws12_l2 = (const float*)d_in[23];
    const float* Wt12_l2 = (const float*)d_in[24];
    const float* a_h0_l1 = (const float*)d_in[25];
    const float* a_h0_l2 = (const float*)d_in[26];
    const float* a_h1_l2 = (const float*)d_in[27];
    const float* a_h2_l2 = (const float*)d_in[28];
    const float* a01_l1 = (const float*)d_in[29];
    const float* a12_l1 = (const float*)d_in[30];
    const float* a01_l2 = (const float*)d_in[31];
    const float* a12_l2 = (const float*)d_in[32];

    // -------- workspace layout (4B units) --------
    float* ws = (float*)d_ws;
    float* A   = ws;                         // [N1,64]
    float* B   = A + 19200000;               // [N1,64]
    float* Cb  = B + 19200000;               // [N0,64]
    float* s0  = Cb + 6400000;
    float* s1  = s0 + 300000;
    float* s2  = s1 + 300000;
    float* s3  = s2 + 300000;
    float* s4  = s3 + 300000;
    float* s5  = s4 + 300000;
    float* uu  = s5 + 300000;                // 128
    int* ip = (int*)(uu + 128);
    int* rpA0 = ip;            ip += CN0 + 1;
    int* rpE1 = ip;            ip += CN0 + 1;
    int* rpF1 = ip;            ip += CN1 + 1;
    int* rpE2 = ip;            ip += CN1 + 1;
    int* rpF2 = ip;            ip += CN2 + 1;
    int* rpA1 = ip;            ip += CN1 + 1;
    int* rpC2 = ip;            ip += CN2 + 1;
    int* vA0 = ip;             ip += EA0;
    int* vE1 = ip;             ip += EB1;
    int* vF1 = ip;             ip += EB1;
    int* vE2 = ip;             ip += EB2;
    int* vF2 = ip;             ip += EB2;
    int* vA1 = ip;             ip += EA1;
    int* vC2 = ip;             ip += EC2;
    int* cnt = ip;             ip += 300000;
    int* bsum = ip;            ip += 2048;

    float* r0 = (float*)d_out;
    float* r1 = r0 + (size_t)CN0 * 64;
    float* r2 = r1 + (size_t)CN1 * 64;

    auto CSR = [&](const int* seg, const int* vidx, int* rp, int* vP, int nseg, int E) {
        hipMemsetAsync(rp, 0, (size_t)(nseg + 1) * 4, stream);
        k_hist<<<dim3((E + 255) / 256), dim3(256), 0, stream>>>(seg, rp, E);
        int nb = (nseg + 255) / 256;
        k_blkscan<<<dim3(nb), dim3(256), 0, stream>>>(rp + 1, nseg, bsum);
        k_scanb<<<dim3(1), dim3(256), 0, stream>>>(bsum, nb);
        k_addoff<<<dim3(nb), dim3(256), 0, stream>>>(rp + 1, bsum, nseg);
        hipMemsetAsync(cnt, 0, (size_t)nseg * 4, stream);
        k_scatter<<<dim3((E + 255) / 256), dim3(256), 0, stream>>>(seg, vidx, rp, cnt, vP, E);
    };
    auto MMF = [&](const float* X, const float* W, const float* a, float* Y,
                   float* p, float* q, int n) {
        int nchunk = n / 16;
        int blocks = min(1024, (nchunk + 3) / 4);
        mm64_mfma<<<dim3(blocks), dim3(256), 0, stream>>>(X, W, a, Y, p, q, nchunk);
    };
    auto PROJ = [&](const float* X, const float* W, const float* a2, float* p, float* q, int n) {
        uvec_k<<<dim3(1), dim3(64), 0, stream>>>(W, a2, uu);
        proj2<<<dim3((n + 3) / 4), dim3(256), 0, stream>>>(X, uu, p, q, n);
    };
    auto AGG = [&](const int* rp, const int* vP, const float* ps, const float* pv,
                   const float* M, float* out, int nseg, int accum) {
        k_seg_attn<<<dim3((nseg + 3) / 4), dim3(256), 0, stream>>>(rp, vP, ps, pv, M, out,
                                                                   nseg, accum);
    };

    // ======== CSR builds ========
    CSR(adj0r, adj0c, rpA0, vA0, CN0, EA0);
    CSR(i1r, i1c, rpE1, vE1, CN0, EB1);
    CSR(i1c, i1r, rpF1, vF1, CN1, EB1);
    CSR(i2r, i2c, rpE2, vE2, CN1, EB2);
    CSR(i2c, i2r, rpF2, vF2, CN2, EB2);
    CSR(adj1r, adj1c, rpA1, vA1, CN1, EA1);
    CSR(co2r, co2c, rpC2, vC2, CN2, EC2);

    // ======== LEVEL 1 ========
    MMF(x0, W_h0_l1, a_h0_l1, Cb, s0, s1, CN0);
    AGG(rpA0, vA0, s0, s1, Cb, r0, CN0, 0);                 // x_0_to_0

    MMF(x1, Ws01_l1, a01_l1, A, s0, s1, CN1);
    MMF(x0, Wt01_l1, a01_l1, Cb, s2, s3, CN0);
    AGG(rpE1, vE1, s3, s0, A, r0, CN0, 1);                  // + x_1_to_0
    AGG(rpF1, vF1, s1, s2, Cb, r1, CN1, 0);                 // x_0_to_1

    MMF(x2, Ws12_l1, a12_l1, A, s0, s1, CN2);
    MMF(x1, Wt12_l1, a12_l1, B, s2, s3, CN1);
    AGG(rpE2, vE2, s3, s0, A, r1, CN1, 1);                  // + x_2_to_1
    AGG(rpF2, vF2, s1, s2, B, r2, CN2, 0);                  // x_1_to_2

    // ======== LEVEL 2 ========
    MMF(r0, W_h0_l2, a_h0_l2, A, s0, s1, CN0);              // m00
    MMF(r0, Wt01_l2, a01_l2, Cb, s4, s5, CN0);              // tm01; pt01 -> s4
    AGG(rpA0, vA0, s0, s1, A, r0, CN0, 0);                  // x_0_out

    MMF(r1, W_h1_l2, a_h1_l2, A, s0, s1, CN1);              // m11
    MMF(r1, Wt12_l2, a12_l2, B, s3, s5, CN1);               // tm12; pt12 -> s3
    PROJ(r1, Ws01_l2, a01_l2, s5, s2, CN1);                 // qs01 -> s2
    AGG(rpA1, vA1, s0, s1, A, r1, CN1, 0);                  // x_1_to_1
    AGG(rpF1, vF1, s2, s4, Cb, r1, CN1, 1);                 // + x_0_to_1

    MMF(r2, W_h2_l2, a_h2_l2, A, s0, s1, CN2);              // m22
    PROJ(r2, Ws12_l2, a12_l2, s5, s2, CN2);                 // qs12 -> s2
    AGG(rpC2, vC2, s0, s1, A, r2, CN2, 0);                  // x_2_to_2
    AGG(rpF2, vF2, s2, s3, B, r2, CN2, 1);                  // + x_1_to_2
}

// Round 6
// 1407.376 us; speedup vs baseline: 3.0401x; 1.3726x over previous
//
#include <hip/hip_runtime.h>

#define CN0 100000
#define CN1 300000
#define CN2 200000
#define EA0 600000
#define EA1 1200000
#define EC2 600000
#define EB1 600000
#define EB2 600000

typedef __attribute__((ext_vector_type(8))) short short8;
typedef __attribute__((ext_vector_type(4))) float f32x4;

__device__ __forceinline__ float lrelu(float v) { return v >= 0.f ? v : 0.2f * v; }
__device__ __forceinline__ unsigned short btop(float x) {
    return (unsigned short)(__float_as_uint(x) >> 16);
}

// ---------------- CSR build kernels ----------------

__global__ void k_hist(const int* __restrict__ seg, int* __restrict__ rp, int E) {
    int e = blockIdx.x * blockDim.x + threadIdx.x;
    if (e < E) atomicAdd(&rp[seg[e] + 1], 1);
}

__global__ void k_blkscan(int* __restrict__ d, int n, int* __restrict__ bsum) {
    __shared__ int sh[256];
    int i = blockIdx.x * 256 + threadIdx.x;
    sh[threadIdx.x] = (i < n) ? d[i] : 0;
    __syncthreads();
    for (int off = 1; off < 256; off <<= 1) {
        int t = (threadIdx.x >= (unsigned)off) ? sh[threadIdx.x - off] : 0;
        __syncthreads();
        sh[threadIdx.x] += t;
        __syncthreads();
    }
    if (i < n) d[i] = sh[threadIdx.x];
    if (threadIdx.x == 255) bsum[blockIdx.x] = sh[255];
}

__global__ void k_scanb(int* __restrict__ bsum, int nb) {
    __shared__ int sh[256];
    __shared__ int carry;
    if (threadIdx.x == 0) carry = 0;
    __syncthreads();
    for (int base = 0; base < nb; base += 256) {
        int i = base + threadIdx.x;
        sh[threadIdx.x] = (i < nb) ? bsum[i] : 0;
        __syncthreads();
        for (int off = 1; off < 256; off <<= 1) {
            int t = (threadIdx.x >= (unsigned)off) ? sh[threadIdx.x - off] : 0;
            __syncthreads();
            sh[threadIdx.x] += t;
            __syncthreads();
        }
        if (i < nb) bsum[i] = sh[threadIdx.x] + carry;
        __syncthreads();
        if (threadIdx.x == 0) carry += sh[255];
        __syncthreads();
    }
}

__global__ void k_addoff(int* __restrict__ d, const int* __restrict__ bsum, int n) {
    int i = blockIdx.x * 256 + threadIdx.x;
    if (i < n && blockIdx.x > 0) d[i] += bsum[blockIdx.x - 1];
}

__global__ void k_scatter(const int* __restrict__ seg, const int* __restrict__ vidx,
                          const int* __restrict__ rp, int* __restrict__ cnt,
                          int* __restrict__ vP, int E) {
    int e = blockIdx.x * blockDim.x + threadIdx.x;
    if (e >= E) return;
    int s = seg[e];
    int pos = rp[s] + atomicAdd(&cnt[s], 1);
    vP[pos] = vidx[e];
}

// ---------------- MFMA matmul (bf16x3 split) ----------------
// Y = X @ W ; fused p = Y@a[0:64], q = Y@a[64:128]
__global__ void mm64_mfma(const float* __restrict__ X, const float* __restrict__ W,
                          const float* __restrict__ a, float* __restrict__ Y,
                          float* __restrict__ p, float* __restrict__ q, int nchunk) {
    int lane = threadIdx.x & 63;
    int l15 = lane & 15, lq = lane >> 4;
    int wid = blockIdx.x * (blockDim.x >> 6) + (threadIdx.x >> 6);
    int nw = gridDim.x * (blockDim.x >> 6);

    short8 bh[4][2], bl[4][2];
#pragma unroll
    for (int t = 0; t < 4; ++t)
#pragma unroll
        for (int h = 0; h < 2; ++h) {
            const float* wp = W + (size_t)(h * 32 + lq * 8) * 64 + 16 * t + l15;
#pragma unroll
            for (int j = 0; j < 8; ++j) {
                float wv = wp[(size_t)j * 64];
                unsigned short hi = btop(wv);
                float rem = wv - __uint_as_float((unsigned)hi << 16);
                bh[t][h][j] = (short)hi;
                bl[t][h][j] = (short)btop(rem);
            }
        }
    float av0[4], av1[4];
#pragma unroll
    for (int t = 0; t < 4; ++t) {
        av0[t] = a[16 * t + l15];
        av1[t] = a[64 + 16 * t + l15];
    }

    for (int c = wid; c < nchunk; c += nw) {
        int base = c * 16;
        f32x4 acc[4];
#pragma unroll
        for (int t = 0; t < 4; ++t) acc[t] = (f32x4){0.f, 0.f, 0.f, 0.f};
#pragma unroll
        for (int h = 0; h < 2; ++h) {
            const f32x4* xp = (const f32x4*)(X + (size_t)(base + l15) * 64 + h * 32 + lq * 8);
            f32x4 x0 = xp[0], x1 = xp[1];
            short8 ah, al;
#pragma unroll
            for (int j = 0; j < 4; ++j) {
                unsigned short h0 = btop(x0[j]);
                float r0 = x0[j] - __uint_as_float((unsigned)h0 << 16);
                ah[j] = (short)h0;
                al[j] = (short)btop(r0);
                unsigned short h1 = btop(x1[j]);
                float r1 = x1[j] - __uint_as_float((unsigned)h1 << 16);
                ah[4 + j] = (short)h1;
                al[4 + j] = (short)btop(r1);
            }
#pragma unroll
            for (int t = 0; t < 4; ++t) {
                acc[t] = __builtin_amdgcn_mfma_f32_16x16x32_bf16(ah, bh[t][h], acc[t], 0, 0, 0);
                acc[t] = __builtin_amdgcn_mfma_f32_16x16x32_bf16(ah, bl[t][h], acc[t], 0, 0, 0);
                acc[t] = __builtin_amdgcn_mfma_f32_16x16x32_bf16(al, bh[t][h], acc[t], 0, 0, 0);
            }
        }
#pragma unroll
        for (int t = 0; t < 4; ++t)
#pragma unroll
            for (int r = 0; r < 4; ++r)
                Y[(size_t)(base + lq * 4 + r) * 64 + 16 * t + l15] = acc[t][r];
#pragma unroll
        for (int r = 0; r < 4; ++r) {
            float pr = acc[0][r] * av0[0] + acc[1][r] * av0[1] + acc[2][r] * av0[2] + acc[3][r] * av0[3];
            float qr = acc[0][r] * av1[0] + acc[1][r] * av1[1] + acc[2][r] * av1[2] + acc[3][r] * av1[3];
#pragma unroll
            for (int off = 8; off; off >>= 1) {
                pr += __shfl_xor(pr, off, 64);
                qr += __shfl_xor(qr, off, 64);
            }
            if (l15 == 0) {
                p[base + lq * 4 + r] = pr;
                q[base + lq * 4 + r] = qr;
            }
        }
    }
}

// uu[j] = W[j,:]@a[0:64]; uu[64+j] = W[j,:]@a[64:128]   (1 block x 64)
__global__ void uvec_k(const float* __restrict__ W, const float* __restrict__ a2c,
                       float* __restrict__ uu) {
    int j = threadIdx.x;
    float s0 = 0.f, s1 = 0.f;
    for (int k = 0; k < 64; ++k) {
        float w = W[j * 64 + k];
        s0 = fmaf(w, a2c[k], s0);
        s1 = fmaf(w, a2c[64 + k], s1);
    }
    uu[j] = s0;
    uu[64 + j] = s1;
}

// p[i] = X[i,:]@uu[0:64], q[i] = X[i,:]@uu[64:128]; one wave per row
__global__ void proj2(const float* __restrict__ X, const float* __restrict__ uu,
                      float* __restrict__ p, float* __restrict__ q, int n) {
    int lane = threadIdx.x & 63;
    int row = blockIdx.x * (blockDim.x >> 6) + (threadIdx.x >> 6);
    if (row >= n) return;
    float xv = X[(size_t)row * 64 + lane];
    float a = xv * uu[lane];
    float b = xv * uu[64 + lane];
#pragma unroll
    for (int off = 32; off; off >>= 1) {
        a += __shfl_xor(a, off, 64);
        b += __shfl_xor(b, off, 64);
    }
    if (lane == 0) { p[row] = a; q[row] = b; }
}

// 16 lanes per segment (4 segments per wave): softmax over edges + weighted
// row gather; each lane owns 4 floats (f32x4) of the 64-float output row.
__global__ void k_seg_attn(const int* __restrict__ rp, const int* __restrict__ vP,
                           const float* __restrict__ ps, const float* __restrict__ pv,
                           const float* __restrict__ M, float* __restrict__ out,
                           int nseg, int accum) {
    int lane = threadIdx.x & 63;
    int g = lane >> 4;       // group in wave
    int gl = lane & 15;      // lane in group
    int gbase = g << 4;      // first abs lane of group
    int s = (blockIdx.x * (blockDim.x >> 6) + (threadIdx.x >> 6)) * 4 + g;
    if (s >= nseg) return;
    int beg = rp[s], end = rp[s + 1];
    int nE = end - beg;
    f32x4* orow = (f32x4*)(out + (size_t)s * 64 + gl * 4);
    if (nE <= 0) {
        if (!accum) *orow = (f32x4){0.f, 0.f, 0.f, 0.f};
        return;
    }
    float pss = ps[s];
    f32x4 acc = (f32x4){0.f, 0.f, 0.f, 0.f};
    if (nE <= 16) {  // fast path: one chunk in registers
        int j = beg + gl;
        int v = (j < end) ? vP[j] : 0;
        float l = (j < end) ? lrelu(pss + pv[v]) : -3.4e38f;
        float mx = l;
#pragma unroll
        for (int off = 8; off; off >>= 1) mx = fmaxf(mx, __shfl_xor(mx, off, 64));
        float ev = (j < end) ? __expf(l - mx) : 0.f;
        float ssum = ev;
#pragma unroll
        for (int off = 8; off; off >>= 1) ssum += __shfl_xor(ssum, off, 64);
        float att = ev / ssum;
        for (int t = 0; t < nE; ++t) {
            float w = __shfl(att, gbase + t, 64);
            int vv = __shfl(v, gbase + t, 64);
            const f32x4 mr = *(const f32x4*)(M + (size_t)vv * 64 + gl * 4);
#pragma unroll
            for (int kk = 0; kk < 4; ++kk) acc[kk] = fmaf(w, mr[kk], acc[kk]);
        }
    } else {  // general path (rare long segments)
        float mx = -3.4e38f;
        for (int j0 = beg; j0 < end; j0 += 16) {
            int j = j0 + gl;
            float l = (j < end) ? lrelu(pss + pv[vP[j]]) : -3.4e38f;
            mx = fmaxf(mx, l);
        }
#pragma unroll
        for (int off = 8; off; off >>= 1) mx = fmaxf(mx, __shfl_xor(mx, off, 64));
        float ssum = 0.f;
        for (int j0 = beg; j0 < end; j0 += 16) {
            int j = j0 + gl;
            ssum += (j < end) ? __expf(lrelu(pss + pv[vP[j]]) - mx) : 0.f;
        }
#pragma unroll
        for (int off = 8; off; off >>= 1) ssum += __shfl_xor(ssum, off, 64);
        float inv = 1.f / ssum;
        for (int j0 = beg; j0 < end; j0 += 16) {
            int j = j0 + gl;
            int v = (j < end) ? vP[j] : 0;
            float ev = (j < end) ? __expf(lrelu(pss + pv[v]) - mx) * inv : 0.f;
            int cnt = min(16, end - j0);
            for (int t = 0; t < cnt; ++t) {
                float w = __shfl(ev, gbase + t, 64);
                int vv = __shfl(v, gbase + t, 64);
                const f32x4 mr = *(const f32x4*)(M + (size_t)vv * 64 + gl * 4);
#pragma unroll
                for (int kk = 0; kk < 4; ++kk) acc[kk] = fmaf(w, mr[kk], acc[kk]);
            }
        }
    }
    if (accum) {
        f32x4 o = *orow;
#pragma unroll
        for (int kk = 0; kk < 4; ++kk) o[kk] += acc[kk];
        *orow = o;
    } else {
        *orow = acc;
    }
}

extern "C" void kernel_launch(void* const* d_in, const int* in_sizes, int n_in,
                              void* d_out, int out_size, void* d_ws, size_t ws_size,
                              hipStream_t stream) {
    (void)in_sizes; (void)n_in; (void)ws_size; (void)out_size;
    const float* x0 = (const float*)d_in[0];
    const float* x1 = (const float*)d_in[1];
    const float* x2 = (const float*)d_in[2];
    const int* adj0r = (const int*)d_in[3];
    const int* adj0c = (const int*)d_in[4];
    const int* adj1r = (const int*)d_in[5];
    const int* adj1c = (const int*)d_in[6];
    const int* co2r = (const int*)d_in[7];
    const int* co2c = (const int*)d_in[8];
    const int* i1r = (const int*)d_in[9];
    const int* i1c = (const int*)d_in[10];
    const int* i2r = (const int*)d_in[11];
    const int* i2c = (const int*)d_in[12];
    const float* W_h0_l1 = (const float*)d_in[13];
    const float* W_h0_l2 = (const float*)d_in[14];
    const float* W_h1_l2 = (const float*)d_in[15];
    const float* W_h2_l2 = (const float*)d_in[16];
    const float* Ws01_l1 = (const float*)d_in[17];
    const float* Wt01_l1 = (const float*)d_in[18];
    const float* Ws12_l1 = (const float*)d_in[19];
    const float* Wt12_l1 = (const float*)d_in[20];
    const float* Ws01_l2 = (const float*)d_in[21];
    const float* Wt01_l2 = (const float*)d_in[22];
    const float* Ws12_l2 = (const float*)d_in[23];
    const float* Wt12_l2 = (const float*)d_in[24];
    const float* a_h0_l1 = (const float*)d_in[25];
    const float* a_h0_l2 = (const float*)d_in[26];
    const float* a_h1_l2 = (const float*)d_in[27];
    const float* a_h2_l2 = (const float*)d_in[28];
    const float* a01_l1 = (const float*)d_in[29];
    const float* a12_l1 = (const float*)d_in[30];
    const float* a01_l2 = (const float*)d_in[31];
    const float* a12_l2 = (const float*)d_in[32];

    // -------- workspace layout (4B units) --------
    float* ws = (float*)d_ws;
    float* A   = ws;                         // [N1,64]
    float* B   = A + 19200000;               // [N1,64]
    float* Cb  = B + 19200000;               // [N0,64]
    float* s0  = Cb + 6400000;
    float* s1  = s0 + 300000;
    float* s2  = s1 + 300000;
    float* s3  = s2 + 300000;
    float* s4  = s3 + 300000;
    float* s5  = s4 + 300000;
    float* uu  = s5 + 300000;                // 128
    int* ip = (int*)(uu + 128);
    int* rpA0 = ip;            ip += CN0 + 1;
    int* rpE1 = ip;            ip += CN0 + 1;
    int* rpF1 = ip;            ip += CN1 + 1;
    int* rpE2 = ip;            ip += CN1 + 1;
    int* rpF2 = ip;            ip += CN2 + 1;
    int* rpA1 = ip;            ip += CN1 + 1;
    int* rpC2 = ip;            ip += CN2 + 1;
    int* vA0 = ip;             ip += EA0;
    int* vE1 = ip;             ip += EB1;
    int* vF1 = ip;             ip += EB1;
    int* vE2 = ip;             ip += EB2;
    int* vF2 = ip;             ip += EB2;
    int* vA1 = ip;             ip += EA1;
    int* vC2 = ip;             ip += EC2;
    int* cnt = ip;             ip += 300000;
    int* bsum = ip;            ip += 2048;

    float* r0 = (float*)d_out;
    float* r1 = r0 + (size_t)CN0 * 64;
    float* r2 = r1 + (size_t)CN1 * 64;

    auto CSR = [&](const int* seg, const int* vidx, int* rp, int* vP, int nseg, int E) {
        hipMemsetAsync(rp, 0, (size_t)(nseg + 1) * 4, stream);
        k_hist<<<dim3((E + 255) / 256), dim3(256), 0, stream>>>(seg, rp, E);
        int nb = (nseg + 255) / 256;
        k_blkscan<<<dim3(nb), dim3(256), 0, stream>>>(rp + 1, nseg, bsum);
        k_scanb<<<dim3(1), dim3(256), 0, stream>>>(bsum, nb);
        k_addoff<<<dim3(nb), dim3(256), 0, stream>>>(rp + 1, bsum, nseg);
        hipMemsetAsync(cnt, 0, (size_t)nseg * 4, stream);
        k_scatter<<<dim3((E + 255) / 256), dim3(256), 0, stream>>>(seg, vidx, rp, cnt, vP, E);
    };
    auto MMF = [&](const float* X, const float* W, const float* a, float* Y,
                   float* p, float* q, int n) {
        int nchunk = n / 16;
        int blocks = min(1024, (nchunk + 3) / 4);
        mm64_mfma<<<dim3(blocks), dim3(256), 0, stream>>>(X, W, a, Y, p, q, nchunk);
    };
    auto PROJ = [&](const float* X, const float* W, const float* a2, float* p, float* q, int n) {
        uvec_k<<<dim3(1), dim3(64), 0, stream>>>(W, a2, uu);
        proj2<<<dim3((n + 3) / 4), dim3(256), 0, stream>>>(X, uu, p, q, n);
    };
    auto AGG = [&](const int* rp, const int* vP, const float* ps, const float* pv,
                   const float* M, float* out, int nseg, int accum) {
        // 16 segments per block (4 waves x 4 groups)
        k_seg_attn<<<dim3((nseg + 15) / 16), dim3(256), 0, stream>>>(rp, vP, ps, pv, M, out,
                                                                     nseg, accum);
    };

    // ======== CSR builds ========
    CSR(adj0r, adj0c, rpA0, vA0, CN0, EA0);
    CSR(i1r, i1c, rpE1, vE1, CN0, EB1);
    CSR(i1c, i1r, rpF1, vF1, CN1, EB1);
    CSR(i2r, i2c, rpE2, vE2, CN1, EB2);
    CSR(i2c, i2r, rpF2, vF2, CN2, EB2);
    CSR(adj1r, adj1c, rpA1, vA1, CN1, EA1);
    CSR(co2r, co2c, rpC2, vC2, CN2, EC2);

    // ======== LEVEL 1 ========
    MMF(x0, W_h0_l1, a_h0_l1, Cb, s0, s1, CN0);
    AGG(rpA0, vA0, s0, s1, Cb, r0, CN0, 0);                 // x_0_to_0

    MMF(x1, Ws01_l1, a01_l1, A, s0, s1, CN1);
    MMF(x0, Wt01_l1, a01_l1, Cb, s2, s3, CN0);
    AGG(rpE1, vE1, s3, s0, A, r0, CN0, 1);                  // + x_1_to_0
    AGG(rpF1, vF1, s1, s2, Cb, r1, CN1, 0);                 // x_0_to_1

    MMF(x2, Ws12_l1, a12_l1, A, s0, s1, CN2);
    MMF(x1, Wt12_l1, a12_l1, B, s2, s3, CN1);
    AGG(rpE2, vE2, s3, s0, A, r1, CN1, 1);                  // + x_2_to_1
    AGG(rpF2, vF2, s1, s2, B, r2, CN2, 0);                  // x_1_to_2

    // ======== LEVEL 2 ========
    MMF(r0, W_h0_l2, a_h0_l2, A, s0, s1, CN0);              // m00
    MMF(r0, Wt01_l2, a01_l2, Cb, s4, s5, CN0);              // tm01; pt01 -> s4
    AGG(rpA0, vA0, s0, s1, A, r0, CN0, 0);                  // x_0_out

    MMF(r1, W_h1_l2, a_h1_l2, A, s0, s1, CN1);              // m11
    MMF(r1, Wt12_l2, a12_l2, B, s3, s5, CN1);               // tm12; pt12 -> s3
    PROJ(r1, Ws01_l2, a01_l2, s5, s2, CN1);                 // qs01 -> s2
    AGG(rpA1, vA1, s0, s1, A, r1, CN1, 0);                  // x_1_to_1
    AGG(rpF1, vF1, s2, s4, Cb, r1, CN1, 1);                 // + x_0_to_1

    MMF(r2, W_h2_l2, a_h2_l2, A, s0, s1, CN2);              // m22
    PROJ(r2, Ws12_l2, a12_l2, s5, s2, CN2);                 // qs12 -> s2
    AGG(rpC2, vC2, s0, s1, A, r2, CN2, 0);                  // x_2_to_2
    AGG(rpF2, vF2, s2, s3, B, r2, CN2, 1);                  // + x_1_to_2
}

// Round 7
// 1161.926 us; speedup vs baseline: 3.6822x; 1.2112x over previous
//
#include <hip/hip_runtime.h>

#define CN0 100000
#define CN1 300000
#define CN2 200000
#define EA0 600000
#define EA1 1200000
#define EC2 600000
#define EB1 600000
#define EB2 600000
#define TOTSEG (2*CN0 + 3*CN1 + 2*CN2)          // 1,500,000
#define TOTE   (EA0 + EA1 + EC2 + 2*EB1 + 2*EB2) // 6,600,000

typedef __attribute__((ext_vector_type(8))) short short8;
typedef __attribute__((ext_vector_type(4))) float f32x4;
typedef __attribute__((ext_vector_type(4))) unsigned short u16x4;

__device__ __forceinline__ float lrelu(float v) { return v >= 0.f ? v : 0.2f * v; }
__device__ __forceinline__ unsigned short btop(float x) {
    return (unsigned short)(__float_as_uint(x) >> 16);
}
// round-to-nearest-even f32 -> bf16
__device__ __forceinline__ unsigned short f2bf(float x) {
    unsigned u = __float_as_uint(x);
    return (unsigned short)((u + 0x7FFFu + ((u >> 16) & 1u)) >> 16);
}
__device__ __forceinline__ float bf2f(unsigned short b) {
    return __uint_as_float((unsigned)b << 16);
}

struct Pats {
    const int* seg[7];
    const int* vidx[7];
    int E[7];
    int base[7];
};

// ---------------- fused CSR build (all 7 patterns) ----------------

__global__ void k_hist7(Pats P, int* __restrict__ rp1) {
    int p = blockIdx.y;
    int e = blockIdx.x * blockDim.x + threadIdx.x;
    if (e < P.E[p]) atomicAdd(&rp1[P.base[p] + P.seg[p][e]], 1);
}

__global__ void k_blkscan(int* __restrict__ d, int n, int* __restrict__ bsum) {
    __shared__ int sh[256];
    int i = blockIdx.x * 256 + threadIdx.x;
    sh[threadIdx.x] = (i < n) ? d[i] : 0;
    __syncthreads();
    for (int off = 1; off < 256; off <<= 1) {
        int t = (threadIdx.x >= (unsigned)off) ? sh[threadIdx.x - off] : 0;
        __syncthreads();
        sh[threadIdx.x] += t;
        __syncthreads();
    }
    if (i < n) d[i] = sh[threadIdx.x];
    if (threadIdx.x == 255) bsum[blockIdx.x] = sh[255];
}

__global__ void k_scanb(int* __restrict__ bsum, int nb) {
    __shared__ int sh[256];
    __shared__ int carry;
    if (threadIdx.x == 0) carry = 0;
    __syncthreads();
    for (int base = 0; base < nb; base += 256) {
        int i = base + threadIdx.x;
        sh[threadIdx.x] = (i < nb) ? bsum[i] : 0;
        __syncthreads();
        for (int off = 1; off < 256; off <<= 1) {
            int t = (threadIdx.x >= (unsigned)off) ? sh[threadIdx.x - off] : 0;
            __syncthreads();
            sh[threadIdx.x] += t;
            __syncthreads();
        }
        if (i < nb) bsum[i] = sh[threadIdx.x] + carry;
        __syncthreads();
        if (threadIdx.x == 0) carry += sh[255];
        __syncthreads();
    }
}

__global__ void k_addoff(int* __restrict__ d, const int* __restrict__ bsum, int n) {
    int i = blockIdx.x * 256 + threadIdx.x;
    if (i < n && blockIdx.x > 0) d[i] += bsum[blockIdx.x - 1];
}

__global__ void k_scat7(Pats P, const int* __restrict__ rp, int* __restrict__ cnt,
                        int* __restrict__ vP) {
    int p = blockIdx.y;
    int e = blockIdx.x * blockDim.x + threadIdx.x;
    if (e >= P.E[p]) return;
    int gs = P.base[p] + P.seg[p][e];
    int pos = rp[gs] + atomicAdd(&cnt[gs], 1);
    vP[pos] = P.vidx[p][e];
}

// ---------------- MFMA matmul (bf16x3 split), bf16 Y output ----------------
// Yb = bf16(X @ W) ; fused f32 p = Y@a[0:64], q = Y@a[64:128]
__global__ void mm64_mfma(const float* __restrict__ X, const float* __restrict__ W,
                          const float* __restrict__ a, unsigned short* __restrict__ Yb,
                          float* __restrict__ p, float* __restrict__ q, int nchunk) {
    int lane = threadIdx.x & 63;
    int l15 = lane & 15, lq = lane >> 4;
    int wid = blockIdx.x * (blockDim.x >> 6) + (threadIdx.x >> 6);
    int nw = gridDim.x * (blockDim.x >> 6);

    short8 bh[4][2], bl[4][2];
#pragma unroll
    for (int t = 0; t < 4; ++t)
#pragma unroll
        for (int h = 0; h < 2; ++h) {
            const float* wp = W + (size_t)(h * 32 + lq * 8) * 64 + 16 * t + l15;
#pragma unroll
            for (int j = 0; j < 8; ++j) {
                float wv = wp[(size_t)j * 64];
                unsigned short hi = btop(wv);
                float rem = wv - __uint_as_float((unsigned)hi << 16);
                bh[t][h][j] = (short)hi;
                bl[t][h][j] = (short)btop(rem);
            }
        }
    float av0[4], av1[4];
#pragma unroll
    for (int t = 0; t < 4; ++t) {
        av0[t] = a[16 * t + l15];
        av1[t] = a[64 + 16 * t + l15];
    }

    for (int c = wid; c < nchunk; c += nw) {
        int base = c * 16;
        f32x4 acc[4];
#pragma unroll
        for (int t = 0; t < 4; ++t) acc[t] = (f32x4){0.f, 0.f, 0.f, 0.f};
#pragma unroll
        for (int h = 0; h < 2; ++h) {
            const f32x4* xp = (const f32x4*)(X + (size_t)(base + l15) * 64 + h * 32 + lq * 8);
            f32x4 x0 = xp[0], x1 = xp[1];
            short8 ah, al;
#pragma unroll
            for (int j = 0; j < 4; ++j) {
                unsigned short h0 = btop(x0[j]);
                float r0 = x0[j] - __uint_as_float((unsigned)h0 << 16);
                ah[j] = (short)h0;
                al[j] = (short)btop(r0);
                unsigned short h1 = btop(x1[j]);
                float r1 = x1[j] - __uint_as_float((unsigned)h1 << 16);
                ah[4 + j] = (short)h1;
                al[4 + j] = (short)btop(r1);
            }
#pragma unroll
            for (int t = 0; t < 4; ++t) {
                acc[t] = __builtin_amdgcn_mfma_f32_16x16x32_bf16(ah, bh[t][h], acc[t], 0, 0, 0);
                acc[t] = __builtin_amdgcn_mfma_f32_16x16x32_bf16(ah, bl[t][h], acc[t], 0, 0, 0);
                acc[t] = __builtin_amdgcn_mfma_f32_16x16x32_bf16(al, bh[t][h], acc[t], 0, 0, 0);
            }
        }
#pragma unroll
        for (int t = 0; t < 4; ++t)
#pragma unroll
            for (int r = 0; r < 4; ++r)
                Yb[(size_t)(base + lq * 4 + r) * 64 + 16 * t + l15] = f2bf(acc[t][r]);
#pragma unroll
        for (int r = 0; r < 4; ++r) {
            float pr = acc[0][r] * av0[0] + acc[1][r] * av0[1] + acc[2][r] * av0[2] + acc[3][r] * av0[3];
            float qr = acc[0][r] * av1[0] + acc[1][r] * av1[1] + acc[2][r] * av1[2] + acc[3][r] * av1[3];
#pragma unroll
            for (int off = 8; off; off >>= 1) {
                pr += __shfl_xor(pr, off, 64);
                qr += __shfl_xor(qr, off, 64);
            }
            if (l15 == 0) {
                p[base + lq * 4 + r] = pr;
                q[base + lq * 4 + r] = qr;
            }
        }
    }
}

// uu[j] = W[j,:]@a[0:64]; uu[64+j] = W[j,:]@a[64:128]   (1 block x 64)
__global__ void uvec_k(const float* __restrict__ W, const float* __restrict__ a2c,
                       float* __restrict__ uu) {
    int j = threadIdx.x;
    float s0 = 0.f, s1 = 0.f;
    for (int k = 0; k < 64; ++k) {
        float w = W[j * 64 + k];
        s0 = fmaf(w, a2c[k], s0);
        s1 = fmaf(w, a2c[64 + k], s1);
    }
    uu[j] = s0;
    uu[64 + j] = s1;
}

// p[i] = X[i,:]@uu[0:64], q[i] = X[i,:]@uu[64:128]; one wave per row
__global__ void proj2(const float* __restrict__ X, const float* __restrict__ uu,
                      float* __restrict__ p, float* __restrict__ q, int n) {
    int lane = threadIdx.x & 63;
    int row = blockIdx.x * (blockDim.x >> 6) + (threadIdx.x >> 6);
    if (row >= n) return;
    float xv = X[(size_t)row * 64 + lane];
    float a = xv * uu[lane];
    float b = xv * uu[64 + lane];
#pragma unroll
    for (int off = 32; off; off >>= 1) {
        a += __shfl_xor(a, off, 64);
        b += __shfl_xor(b, off, 64);
    }
    if (lane == 0) { p[row] = a; q[row] = b; }
}

// 16 lanes per segment (4 segments per wave): softmax over edges + weighted
// bf16-row gather; each lane owns 4 elems of the 64-float output row.
__global__ void k_seg_attn(const int* __restrict__ rp, const int* __restrict__ vP,
                           const float* __restrict__ ps, const float* __restrict__ pv,
                           const unsigned short* __restrict__ Mb, float* __restrict__ out,
                           int nseg, int accum) {
    int lane = threadIdx.x & 63;
    int g = lane >> 4;
    int gl = lane & 15;
    int gbase = g << 4;
    int s = (blockIdx.x * (blockDim.x >> 6) + (threadIdx.x >> 6)) * 4 + g;
    if (s >= nseg) return;
    int beg = rp[s], end = rp[s + 1];
    int nE = end - beg;
    f32x4* orow = (f32x4*)(out + (size_t)s * 64 + gl * 4);
    if (nE <= 0) {
        if (!accum) *orow = (f32x4){0.f, 0.f, 0.f, 0.f};
        return;
    }
    float pss = ps[s];
    f32x4 acc = (f32x4){0.f, 0.f, 0.f, 0.f};
    if (nE <= 16) {  // fast path
        int j = beg + gl;
        int v = (j < end) ? vP[j] : 0;
        float l = (j < end) ? lrelu(pss + pv[v]) : -3.4e38f;
        float mx = l;
#pragma unroll
        for (int off = 8; off; off >>= 1) mx = fmaxf(mx, __shfl_xor(mx, off, 64));
        float ev = (j < end) ? __expf(l - mx) : 0.f;
        float ssum = ev;
#pragma unroll
        for (int off = 8; off; off >>= 1) ssum += __shfl_xor(ssum, off, 64);
        float att = ev / ssum;
        for (int t = 0; t < nE; ++t) {
            float w = __shfl(att, gbase + t, 64);
            int vv = __shfl(v, gbase + t, 64);
            const u16x4 mv = *(const u16x4*)(Mb + (size_t)vv * 64 + gl * 4);
#pragma unroll
            for (int kk = 0; kk < 4; ++kk) acc[kk] = fmaf(w, bf2f(mv[kk]), acc[kk]);
        }
    } else {  // general path (rare long segments)
        float mx = -3.4e38f;
        for (int j0 = beg; j0 < end; j0 += 16) {
            int j = j0 + gl;
            float l = (j < end) ? lrelu(pss + pv[vP[j]]) : -3.4e38f;
            mx = fmaxf(mx, l);
        }
#pragma unroll
        for (int off = 8; off; off >>= 1) mx = fmaxf(mx, __shfl_xor(mx, off, 64));
        float ssum = 0.f;
        for (int j0 = beg; j0 < end; j0 += 16) {
            int j = j0 + gl;
            ssum += (j < end) ? __expf(lrelu(pss + pv[vP[j]]) - mx) : 0.f;
        }
#pragma unroll
        for (int off = 8; off; off >>= 1) ssum += __shfl_xor(ssum, off, 64);
        float inv = 1.f / ssum;
        for (int j0 = beg; j0 < end; j0 += 16) {
            int j = j0 + gl;
            int v = (j < end) ? vP[j] : 0;
            float ev = (j < end) ? __expf(lrelu(pss + pv[v]) - mx) * inv : 0.f;
            int cnt = min(16, end - j0);
            for (int t = 0; t < cnt; ++t) {
                float w = __shfl(ev, gbase + t, 64);
                int vv = __shfl(v, gbase + t, 64);
                const u16x4 mv = *(const u16x4*)(Mb + (size_t)vv * 64 + gl * 4);
#pragma unroll
                for (int kk = 0; kk < 4; ++kk) acc[kk] = fmaf(w, bf2f(mv[kk]), acc[kk]);
            }
        }
    }
    if (accum) {
        f32x4 o = *orow;
#pragma unroll
        for (int kk = 0; kk < 4; ++kk) o[kk] += acc[kk];
        *orow = o;
    } else {
        *orow = acc;
    }
}

extern "C" void kernel_launch(void* const* d_in, const int* in_sizes, int n_in,
                              void* d_out, int out_size, void* d_ws, size_t ws_size,
                              hipStream_t stream) {
    (void)in_sizes; (void)n_in; (void)ws_size; (void)out_size;
    const float* x0 = (const float*)d_in[0];
    const float* x1 = (const float*)d_in[1];
    const float* x2 = (const float*)d_in[2];
    const int* adj0r = (const int*)d_in[3];
    const int* adj0c = (const int*)d_in[4];
    const int* adj1r = (const int*)d_in[5];
    const int* adj1c = (const int*)d_in[6];
    const int* co2r = (const int*)d_in[7];
    const int* co2c = (const int*)d_in[8];
    const int* i1r = (const int*)d_in[9];
    const int* i1c = (const int*)d_in[10];
    const int* i2r = (const int*)d_in[11];
    const int* i2c = (const int*)d_in[12];
    const float* W_h0_l1 = (const float*)d_in[13];
    const float* W_h0_l2 = (const float*)d_in[14];
    const float* W_h1_l2 = (const float*)d_in[15];
    const float* W_h2_l2 = (const float*)d_in[16];
    const float* Ws01_l1 = (const float*)d_in[17];
    const float* Wt01_l1 = (const float*)d_in[18];
    const float* Ws12_l1 = (const float*)d_in[19];
    const float* Wt12_l1 = (const float*)d_in[20];
    const float* Ws01_l2 = (const float*)d_in[21];
    const float* Wt01_l2 = (const float*)d_in[22];
    const float* Ws12_l2 = (const float*)d_in[23];
    const float* Wt12_l2 = (const float*)d_in[24];
    const float* a_h0_l1 = (const float*)d_in[25];
    const float* a_h0_l2 = (const float*)d_in[26];
    const float* a_h1_l2 = (const float*)d_in[27];
    const float* a_h2_l2 = (const float*)d_in[28];
    const float* a01_l1 = (const float*)d_in[29];
    const float* a12_l1 = (const float*)d_in[30];
    const float* a01_l2 = (const float*)d_in[31];
    const float* a12_l2 = (const float*)d_in[32];

    // -------- workspace layout --------
    float* ws = (float*)d_ws;
    float* s0 = ws;
    float* s1 = s0 + 300000;
    float* s2 = s1 + 300000;
    float* s3 = s2 + 300000;
    float* s4 = s3 + 300000;
    float* s5 = s4 + 300000;
    float* uu = s5 + 300000;                         // 128
    unsigned short* Ab  = (unsigned short*)(uu + 128);  // [N1*64] bf16
    unsigned short* Bb  = Ab + (size_t)CN1 * 64;        // [N1*64] bf16
    unsigned short* Cbb = Bb + (size_t)CN1 * 64;        // [N0*64] bf16
    int* rp_all  = (int*)(Cbb + (size_t)CN0 * 64);      // TOTSEG+1
    int* cnt_all = rp_all + (TOTSEG + 1);               // TOTSEG
    int* vP_all  = cnt_all + TOTSEG;                    // TOTE
    int* bsum    = vP_all + TOTE;                       // 8192

    float* r0 = (float*)d_out;
    float* r1 = r0 + (size_t)CN0 * 64;
    float* r2 = r1 + (size_t)CN1 * 64;

    // pattern order: A0, E1, F1, E2, F2, A1, C2
    const int bA0 = 0;
    const int bE1 = CN0;
    const int bF1 = 2 * CN0;
    const int bE2 = 2 * CN0 + CN1;
    const int bF2 = 2 * CN0 + 2 * CN1;
    const int bA1 = 2 * CN0 + 2 * CN1 + CN2;
    const int bC2 = 2 * CN0 + 3 * CN1 + CN2;
    Pats P;
    P.seg[0] = adj0r; P.vidx[0] = adj0c; P.E[0] = EA0; P.base[0] = bA0;
    P.seg[1] = i1r;   P.vidx[1] = i1c;   P.E[1] = EB1; P.base[1] = bE1;
    P.seg[2] = i1c;   P.vidx[2] = i1r;   P.E[2] = EB1; P.base[2] = bF1;
    P.seg[3] = i2r;   P.vidx[3] = i2c;   P.E[3] = EB2; P.base[3] = bE2;
    P.seg[4] = i2c;   P.vidx[4] = i2r;   P.E[4] = EB2; P.base[4] = bF2;
    P.seg[5] = adj1r; P.vidx[5] = adj1c; P.E[5] = EA1; P.base[5] = bA1;
    P.seg[6] = co2r;  P.vidx[6] = co2c;  P.E[6] = EC2; P.base[6] = bC2;
    const int Emax = EA1;

    auto MMF = [&](const float* X, const float* W, const float* a, unsigned short* Yb,
                   float* p, float* q, int n) {
        int nchunk = n / 16;
        int blocks = min(1024, (nchunk + 3) / 4);
        mm64_mfma<<<dim3(blocks), dim3(256), 0, stream>>>(X, W, a, Yb, p, q, nchunk);
    };
    auto PROJ = [&](const float* X, const float* W, const float* a2, float* p, float* q, int n) {
        uvec_k<<<dim3(1), dim3(64), 0, stream>>>(W, a2, uu);
        proj2<<<dim3((n + 3) / 4), dim3(256), 0, stream>>>(X, uu, p, q, n);
    };
    auto AGG = [&](int base, const float* ps, const float* pv, const unsigned short* Mb,
                   float* out, int nseg, int accum) {
        k_seg_attn<<<dim3((nseg + 15) / 16), dim3(256), 0, stream>>>(
            rp_all + base, vP_all, ps, pv, Mb, out, nseg, accum);
    };

    // ======== fused CSR build ========
    hipMemsetAsync(rp_all, 0, (size_t)(TOTSEG + 1) * 4, stream);
    {
        dim3 g((Emax + 255) / 256, 7);
        k_hist7<<<g, dim3(256), 0, stream>>>(P, rp_all + 1);
        int nb = (TOTSEG + 255) / 256;
        k_blkscan<<<dim3(nb), dim3(256), 0, stream>>>(rp_all + 1, TOTSEG, bsum);
        k_scanb<<<dim3(1), dim3(256), 0, stream>>>(bsum, nb);
        k_addoff<<<dim3(nb), dim3(256), 0, stream>>>(rp_all + 1, bsum, TOTSEG);
        hipMemsetAsync(cnt_all, 0, (size_t)TOTSEG * 4, stream);
        k_scat7<<<g, dim3(256), 0, stream>>>(P, rp_all, cnt_all, vP_all);
    }

    // ======== LEVEL 1 ========
    MMF(x0, W_h0_l1, a_h0_l1, Cbb, s0, s1, CN0);
    AGG(bA0, s0, s1, Cbb, r0, CN0, 0);                  // x_0_to_0

    MMF(x1, Ws01_l1, a01_l1, Ab, s0, s1, CN1);
    MMF(x0, Wt01_l1, a01_l1, Cbb, s2, s3, CN0);
    AGG(bE1, s3, s0, Ab, r0, CN0, 1);                   // + x_1_to_0
    AGG(bF1, s1, s2, Cbb, r1, CN1, 0);                  // x_0_to_1

    MMF(x2, Ws12_l1, a12_l1, Ab, s0, s1, CN2);
    MMF(x1, Wt12_l1, a12_l1, Bb, s2, s3, CN1);
    AGG(bE2, s3, s0, Ab, r1, CN1, 1);                   // + x_2_to_1
    AGG(bF2, s1, s2, Bb, r2, CN2, 0);                   // x_1_to_2

    // ======== LEVEL 2 ========
    // rank 0: consume r0 (=x0_l1), then overwrite with x_0_out
    MMF(r0, W_h0_l2, a_h0_l2, Ab, s0, s1, CN0);         // m00
    MMF(r0, Wt01_l2, a01_l2, Cbb, s4, s5, CN0);         // tm01 bf16; pt01 -> s4
    AGG(bA0, s0, s1, Ab, r0, CN0, 0);                   // x_0_out

    // rank 1: consume r1 (=x1_l1), then overwrite with x_1_out
    MMF(r1, W_h1_l2, a_h1_l2, Ab, s0, s1, CN1);         // m11
    MMF(r1, Wt12_l2, a12_l2, Bb, s3, s5, CN1);          // tm12 bf16; pt12 -> s3
    PROJ(r1, Ws01_l2, a01_l2, s5, s2, CN1);             // qs01 -> s2
    AGG(bA1, s0, s1, Ab, r1, CN1, 0);                   // x_1_to_1
    AGG(bF1, s2, s4, Cbb, r1, CN1, 1);                  // + x_0_to_1

    // rank 2: consume r2 (=x2_l1), then overwrite with x_2_out
    MMF(r2, W_h2_l2, a_h2_l2, Ab, s0, s1, CN2);         // m22
    PROJ(r2, Ws12_l2, a12_l2, s5, s2, CN2);             // qs12 -> s2
    AGG(bC2, s0, s1, Ab, r2, CN2, 0);                   // x_2_to_2
    AGG(bF2, s2, s3, Bb, r2, CN2, 1);                   // + x_1_to_2
}